// Round 7
// baseline (211.679 us; speedup 1.0000x reference)
//
#include <hip/hip_runtime.h>

// Aggregationlayer: coord = clip(x) + mean_k clip(trans)
//                   h = hh + silu([hh | sum_k ef] @ W1 + b1) @ W2 + b2
// R6 = R5 (best, 195.4us) with ONE change: edge loads are plain (not
//     non-temporal). Theory: nt-hint on reads defeats L2 sector combining
//     -> the ~4.8 TB/s read ceiling seen in every nt-variant incl. the pure
//     streamer. wb/hh L2-residency no longer needs nt (residual from LDS).

typedef float f32x4 __attribute__((ext_vector_type(4)));
typedef short short8 __attribute__((ext_vector_type(8)));
typedef short short4v __attribute__((ext_vector_type(4)));

#define KNB 16
#define HNF 256
#define W1E (512 * 256)
#define W2E (256 * 256)
#define WB_BYTES ((size_t)(W1E + W2E) * 2)

__device__ __forceinline__ short f2bf(float f) {
  unsigned u = __builtin_bit_cast(unsigned, f);
  u += 0x7fffu + ((u >> 16) & 1u);   // round-to-nearest-even
  return (short)(u >> 16);
}

__device__ __forceinline__ float bf2f(short s) {
  unsigned u = ((unsigned)(unsigned short)s) << 16;
  return __builtin_bit_cast(float, u);
}

__device__ __forceinline__ float clipf(float v) {
  return fminf(fmaxf(v, -1000.f), 1000.f);
}

// ---- pre-kernel: f32 weights -> bf16 fragment layout -----------------------
// dst[(((k>>5)*256 + col)<<5) + ((k>>3)&3)*8 + (k&7)] = bf16(W[k][col])
__global__ void convw(const float* __restrict__ W1, const float* __restrict__ W2,
                      short* __restrict__ wb) {
  int i = blockIdx.x * 256 + threadIdx.x;
  const float* src; short* dst; int k, col;
  if (i < W1E) { src = W1; dst = wb; k = i >> 8; col = i & 255; }
  else         { int j = i - W1E; src = W2; dst = wb + W1E; k = j >> 8; col = j & 255; }
  short v = f2bf(src[((size_t)k << 8) | col]);
  dst[(((k >> 5) * 256 + col) << 5) + ((k >> 3) & 3) * 8 + (k & 7)] = v;
}

// ---- fused main kernel (R5 structure, occupancy 5) --------------------------
__global__ __launch_bounds__(256, 5) void agg_fused5(
    const float* __restrict__ x, const float* __restrict__ trans,
    const float* __restrict__ edge, const float* __restrict__ hh,
    const float* __restrict__ b1, const float* __restrict__ b2,
    const short* __restrict__ wb,
    float* __restrict__ coord_out, float* __restrict__ h_out, int N) {
  // agg tile [32][512] bf16 (row stride 1024B), XOR-swizzled. 32 KB.
  // cols 0..255 = hh (live until epilogue), 256..511 = ef (T overwrites it).
  __shared__ __align__(16) char smem[32 * 1024];

  const int t = threadIdx.x;
  const int w = t >> 6, lane = t & 63;
  const int r0 = blockIdx.x * 32;

  // ---------------- coord (f32 exact) ----------------
  if (lane < 8) {
    int grow = r0 + w * 8 + lane;
    if (grow < N) {
      float cx[3], s[3];
#pragma unroll
      for (int d = 0; d < 3; ++d) { cx[d] = clipf(x[(size_t)grow * 3 + d]); s[d] = 0.f; }
      const float* tp = trans + (size_t)grow * 48;
#pragma unroll
      for (int q = 0; q < 12; ++q) {
        f32x4 v = *(const f32x4*)(tp + q * 4);
#pragma unroll
        for (int e = 0; e < 4; ++e) s[(q * 4 + e) % 3] += clipf(v[e]);
      }
#pragma unroll
      for (int d = 0; d < 3; ++d)
        coord_out[(size_t)grow * 3 + d] = cx[d] + s[d] * (1.f / 16.f);
    }
  }

  // ---------------- stage agg = [hh | sum_k edge] as bf16 ----------------
  // wave w handles row i0+w; 64 lanes cover 256 cols as float4.
#pragma unroll
  for (int i0 = 0; i0 < 32; i0 += 4) {
    int row = i0 + w;
    int grow = r0 + row;
    f32x4 ef = {0.f, 0.f, 0.f, 0.f};
    f32x4 hv = {0.f, 0.f, 0.f, 0.f};
    if (grow < N) {
      const float* ep = edge + (size_t)grow * (KNB * HNF) + lane * 4;
#pragma unroll
      for (int k = 0; k < KNB; ++k) ef += *(const f32x4*)(ep + k * HNF);   // plain loads
      hv = *(const f32x4*)(hh + (size_t)grow * HNF + lane * 4);
    }
    short4v hb, eb;
#pragma unroll
    for (int j = 0; j < 4; ++j) { hb[j] = f2bf(hv[j]); eb[j] = f2bf(ef[j]); }
    int sw = (row & 7) << 4;
    *(short4v*)(smem + ((row * 1024 + lane * 8) ^ sw)) = hb;
    *(short4v*)(smem + ((row * 1024 + 512 + lane * 8) ^ sw)) = eb;
  }
  __syncthreads();

  // ---------------- mat1: T = silu([hh|ef] @ W1 + b1) ----------------
  const int colbase = w * 64;
  const int mrow = lane & 15;    // A row / C col within 16-tile
  const int kslot = lane >> 4;   // k-slot within 32-step
  const short8* wf1 = (const short8*)wb;
  const short8* wf2 = (const short8*)(wb + W1E);

  f32x4 acc1[2][4];
#pragma unroll
  for (int mt = 0; mt < 2; ++mt)
#pragma unroll
    for (int nt = 0; nt < 4; ++nt) acc1[mt][nt] = (f32x4){0.f, 0.f, 0.f, 0.f};

#pragma unroll 2
  for (int kk = 0; kk < 16; ++kk) {
    int k0 = kk * 32 + kslot * 8;
    int swa = (mrow & 7) << 4;
    short8 a0 = *(const short8*)(smem + ((mrow * 1024 + k0 * 2) ^ swa));
    short8 a1 = *(const short8*)(smem + (((16 + mrow) * 1024 + k0 * 2) ^ swa));
    const short8* base = wf1 + ((kk * 256 + colbase + mrow) * 4 + kslot);
#pragma unroll
    for (int nt = 0; nt < 4; ++nt) {
      short8 bw = base[nt * 64];
      acc1[0][nt] = __builtin_amdgcn_mfma_f32_16x16x32_bf16(a0, bw, acc1[0][nt], 0, 0, 0);
      acc1[1][nt] = __builtin_amdgcn_mfma_f32_16x16x32_bf16(a1, bw, acc1[1][nt], 0, 0, 0);
    }
  }

  float b1v[4];
#pragma unroll
  for (int nt = 0; nt < 4; ++nt) b1v[nt] = b1[colbase + nt * 16 + mrow];

  __syncthreads();   // all waves done reading ef fragments before T overwrites

  // silu + T write into the ef half (bytes row*1024+512..+1023, swizzled).
  // C/D mapping: row=(lane>>4)*4+reg (+mt*16), col=lane&15 (+colbase+nt*16).
#pragma unroll
  for (int mt = 0; mt < 2; ++mt)
#pragma unroll
    for (int nt = 0; nt < 4; ++nt)
#pragma unroll
      for (int r = 0; r < 4; ++r) {
        float v = acc1[mt][nt][r] + b1v[nt];
        v = v / (1.f + __expf(-v));
        int row = mt * 16 + kslot * 4 + r;
        int col = colbase + nt * 16 + mrow;
        unsigned off = ((unsigned)(row * 1024 + 512 + col * 2)) ^ ((row & 7) << 4);
        *(short*)(smem + off) = f2bf(v);
      }
  __syncthreads();

  // ---------------- mat2: h = T @ W2 + b2 + hh(LDS) ----------------
  f32x4 acc2[2][4];
#pragma unroll
  for (int mt = 0; mt < 2; ++mt)
#pragma unroll
    for (int nt = 0; nt < 4; ++nt) acc2[mt][nt] = (f32x4){0.f, 0.f, 0.f, 0.f};

#pragma unroll 2
  for (int kk = 0; kk < 8; ++kk) {
    int k0 = kk * 32 + kslot * 8;
    const short8* base = wf2 + ((kk * 256 + colbase + mrow) * 4 + kslot);
#pragma unroll
    for (int mt = 0; mt < 2; ++mt) {
      int arow = mt * 16 + mrow;
      short8 a = *(const short8*)(smem + (((unsigned)(arow * 1024 + 512 + k0 * 2)) ^ ((arow & 7) << 4)));
#pragma unroll
      for (int nt = 0; nt < 4; ++nt)
        acc2[mt][nt] = __builtin_amdgcn_mfma_f32_16x16x32_bf16(a, base[nt * 64], acc2[mt][nt], 0, 0, 0);
    }
  }

#pragma unroll
  for (int nt = 0; nt < 4; ++nt) {
    int col = colbase + nt * 16 + mrow;
    float bv = b2[col];
#pragma unroll
    for (int mt = 0; mt < 2; ++mt)
#pragma unroll
      for (int r = 0; r < 4; ++r) {
        int row = mt * 16 + kslot * 4 + r;
        int grow = r0 + row;
        if (grow < N) {
          // residual from the staged bf16 hh tile (hh half still intact)
          unsigned hoff = ((unsigned)(row * 1024 + col * 2)) ^ ((row & 7) << 4);
          float hres = bf2f(*(const short*)(smem + hoff));
          size_t idx = (size_t)grow * HNF + col;
          float res = acc2[mt][nt][r] + bv + hres;
          __builtin_nontemporal_store(res, &h_out[idx]);
        }
      }
  }
}

// ---- fallback (ws too small for wb): inline weight conversion --------------
__device__ __forceinline__ short8 load_wfrag(const float* __restrict__ W, int k0, int col) {
  short8 r;
#pragma unroll
  for (int j = 0; j < 8; ++j) r[j] = f2bf(W[(size_t)(k0 + j) * 256 + col]);
  return r;
}

__global__ __launch_bounds__(256, 4) void agg_fallback(
    const float* __restrict__ x, const float* __restrict__ trans,
    const float* __restrict__ edge, const float* __restrict__ hh,
    const float* __restrict__ W1, const float* __restrict__ b1,
    const float* __restrict__ W2, const float* __restrict__ b2,
    float* __restrict__ coord_out, float* __restrict__ h_out, int N) {
  __shared__ __align__(16) char smem[32 * 512 * 2];
  const int t = threadIdx.x, w = t >> 6, lane = t & 63;
  const int r0 = blockIdx.x * 32;
  if (lane < 8) {
    int grow = r0 + w * 8 + lane;
    if (grow < N) {
      float cx[3], s[3];
#pragma unroll
      for (int d = 0; d < 3; ++d) { cx[d] = clipf(x[(size_t)grow * 3 + d]); s[d] = 0.f; }
      const float* tp = trans + (size_t)grow * 48;
#pragma unroll
      for (int q = 0; q < 12; ++q) {
        f32x4 v = *(const f32x4*)(tp + q * 4);
#pragma unroll
        for (int e = 0; e < 4; ++e) s[(q * 4 + e) % 3] += clipf(v[e]);
      }
#pragma unroll
      for (int d = 0; d < 3; ++d)
        coord_out[(size_t)grow * 3 + d] = cx[d] + s[d] * (1.f / 16.f);
    }
  }
#pragma unroll
  for (int i0 = 0; i0 < 32; i0 += 4) {
    int row = i0 + w, grow = r0 + row;
    f32x4 ef = {0.f, 0.f, 0.f, 0.f}, hv = {0.f, 0.f, 0.f, 0.f};
    if (grow < N) {
      const float* ep = edge + (size_t)grow * (16 * 256) + lane * 4;
#pragma unroll
      for (int k = 0; k < 16; ++k) ef += *(const f32x4*)(ep + k * 256);
      hv = *(const f32x4*)(hh + (size_t)grow * 256 + lane * 4);
    }
    short4v hb, ebv;
#pragma unroll
    for (int j = 0; j < 4; ++j) { hb[j] = f2bf(hv[j]); ebv[j] = f2bf(ef[j]); }
    int sw = (row & 7) << 4;
    *(short4v*)(smem + ((row * 1024 + lane * 8) ^ sw)) = hb;
    *(short4v*)(smem + ((row * 1024 + 512 + lane * 8) ^ sw)) = ebv;
  }
  __syncthreads();
  const int colbase = w * 64, mrow = lane & 15, kslot = lane >> 4, kgrp = kslot * 8;
  f32x4 acc1[2][4];
#pragma unroll
  for (int mt = 0; mt < 2; ++mt)
#pragma unroll
    for (int nt = 0; nt < 4; ++nt) acc1[mt][nt] = (f32x4){0.f, 0.f, 0.f, 0.f};
#pragma unroll 2
  for (int kk = 0; kk < 16; ++kk) {
    int k0 = kk * 32 + kgrp, swa = (mrow & 7) << 4;
    short8 a0 = *(const short8*)(smem + ((mrow * 1024 + k0 * 2) ^ swa));
    short8 a1 = *(const short8*)(smem + (((16 + mrow) * 1024 + k0 * 2) ^ swa));
#pragma unroll
    for (int nt = 0; nt < 4; ++nt) {
      short8 bw = load_wfrag(W1, k0, colbase + nt * 16 + mrow);
      acc1[0][nt] = __builtin_amdgcn_mfma_f32_16x16x32_bf16(a0, bw, acc1[0][nt], 0, 0, 0);
      acc1[1][nt] = __builtin_amdgcn_mfma_f32_16x16x32_bf16(a1, bw, acc1[1][nt], 0, 0, 0);
    }
  }
  float b1v[4];
#pragma unroll
  for (int nt = 0; nt < 4; ++nt) b1v[nt] = b1[colbase + nt * 16 + mrow];
  __syncthreads();
#pragma unroll
  for (int mt = 0; mt < 2; ++mt)
#pragma unroll
    for (int nt = 0; nt < 4; ++nt)
#pragma unroll
      for (int r = 0; r < 4; ++r) {
        float v = acc1[mt][nt][r] + b1v[nt];
        v = v / (1.f + __expf(-v));
        int row = mt * 16 + kslot * 4 + r, col = colbase + nt * 16 + mrow;
        *(short*)(smem + ((row * 512 + col * 2) ^ ((row & 7) << 4))) = f2bf(v);
      }
  __syncthreads();
  f32x4 acc2[2][4];
#pragma unroll
  for (int mt = 0; mt < 2; ++mt)
#pragma unroll
    for (int nt = 0; nt < 4; ++nt) acc2[mt][nt] = (f32x4){0.f, 0.f, 0.f, 0.f};
#pragma unroll 2
  for (int kk = 0; kk < 8; ++kk) {
    int k0 = kk * 32 + kgrp;
#pragma unroll
    for (int mt = 0; mt < 2; ++mt) {
      int arow = mt * 16 + mrow;
      short8 a = *(const short8*)(smem + ((arow * 512 + k0 * 2) ^ ((arow & 7) << 4)));
#pragma unroll
      for (int nt = 0; nt < 4; ++nt) {
        short8 bw = load_wfrag(W2, k0, colbase + nt * 16 + mrow);
        acc2[mt][nt] = __builtin_amdgcn_mfma_f32_16x16x32_bf16(a, bw, acc2[mt][nt], 0, 0, 0);
      }
    }
  }
#pragma unroll
  for (int mt = 0; mt < 2; ++mt)
#pragma unroll
    for (int nt = 0; nt < 4; ++nt) {
      int col = colbase + nt * 16 + mrow;
      float bv = b2[col];
#pragma unroll
      for (int r = 0; r < 4; ++r) {
        int row = mt * 16 + kslot * 4 + r, grow = r0 + row;
        if (grow < N) {
          size_t idx = (size_t)grow * 256 + col;
          h_out[idx] = acc2[mt][nt][r] + bv + hh[idx];
        }
      }
    }
}

extern "C" void kernel_launch(void* const* d_in, const int* in_sizes, int n_in,
                              void* d_out, int out_size, void* d_ws, size_t ws_size,
                              hipStream_t stream) {
  const float* x     = (const float*)d_in[0];
  const float* trans = (const float*)d_in[1];
  const float* edge  = (const float*)d_in[2];
  const float* hh    = (const float*)d_in[3];
  const float* W1    = (const float*)d_in[4];
  const float* b1    = (const float*)d_in[5];
  const float* W2    = (const float*)d_in[6];
  const float* b2    = (const float*)d_in[7];

  int N = in_sizes[0] / 3;
  float* coord_out = (float*)d_out;
  float* h_out = coord_out + (size_t)N * 3;
  int grid = (N + 31) / 32;

  if (ws_size >= WB_BYTES) {
    short* wb = (short*)d_ws;
    convw<<<(W1E + W2E) / 256, 256, 0, stream>>>(W1, W2, wb);
    agg_fused5<<<grid, 256, 0, stream>>>(x, trans, edge, hh, b1, b2, wb,
                                         coord_out, h_out, N);
  } else {
    agg_fallback<<<grid, 256, 0, stream>>>(x, trans, edge, hh, W1, b1, W2, b2,
                                           coord_out, h_out, N);
  }
}

// Round 8
// 204.858 us; speedup vs baseline: 1.0333x; 1.0333x over previous
//
#include <hip/hip_runtime.h>

// Aggregationlayer: coord = clip(x) + mean_k clip(trans)
//                   h = hh + silu([hh | sum_k ef] @ W1 + b1) @ W2 + b2
// R7 = R5 structure (best, 195.4us; nt edge loads RESTORED after R6 proved
//     they protect L2-resident weights) with tile halved for tail reduction:
//     MT=16 -> grid 3125 (exact), T_block halves, makespan 2.0->1.5 T_b(32);
//     __launch_bounds__(256,6): 24 waves/CU (VGPR cap 85; LDS 16KB/block).

typedef float f32x4 __attribute__((ext_vector_type(4)));
typedef short short8 __attribute__((ext_vector_type(8)));
typedef short short4v __attribute__((ext_vector_type(4)));

#define MT 16
#define KNB 16
#define HNF 256
#define W1E (512 * 256)
#define W2E (256 * 256)
#define WB_BYTES ((size_t)(W1E + W2E) * 2)

__device__ __forceinline__ short f2bf(float f) {
  unsigned u = __builtin_bit_cast(unsigned, f);
  u += 0x7fffu + ((u >> 16) & 1u);   // round-to-nearest-even
  return (short)(u >> 16);
}

__device__ __forceinline__ float bf2f(short s) {
  unsigned u = ((unsigned)(unsigned short)s) << 16;
  return __builtin_bit_cast(float, u);
}

__device__ __forceinline__ float clipf(float v) {
  return fminf(fmaxf(v, -1000.f), 1000.f);
}

__device__ __forceinline__ f32x4 ldnt4(const float* p) {
  return __builtin_nontemporal_load((const f32x4*)p);
}

// ---- pre-kernel: f32 weights -> bf16 fragment layout -----------------------
// dst[(((k>>5)*256 + col)<<5) + ((k>>3)&3)*8 + (k&7)] = bf16(W[k][col])
__global__ void convw(const float* __restrict__ W1, const float* __restrict__ W2,
                      short* __restrict__ wb) {
  int i = blockIdx.x * 256 + threadIdx.x;
  const float* src; short* dst; int k, col;
  if (i < W1E) { src = W1; dst = wb; k = i >> 8; col = i & 255; }
  else         { int j = i - W1E; src = W2; dst = wb + W1E; k = j >> 8; col = j & 255; }
  short v = f2bf(src[((size_t)k << 8) | col]);
  dst[(((k >> 5) * 256 + col) << 5) + ((k >> 3) & 3) * 8 + (k & 7)] = v;
}

// ---- fused main kernel (MT=16, occupancy 6) --------------------------------
__global__ __launch_bounds__(256, 6) void agg_fused6(
    const float* __restrict__ x, const float* __restrict__ trans,
    const float* __restrict__ edge, const float* __restrict__ hh,
    const float* __restrict__ b1, const float* __restrict__ b2,
    const short* __restrict__ wb,
    float* __restrict__ coord_out, float* __restrict__ h_out, int N) {
  // agg tile [16][512] bf16 (row stride 1024B), XOR-swizzled. 16 KB.
  // cols 0..255 = hh (live until epilogue), 256..511 = ef (T overwrites it).
  __shared__ __align__(16) char smem[MT * 1024];

  const int t = threadIdx.x;
  const int w = t >> 6, lane = t & 63;
  const int r0 = blockIdx.x * MT;

  // ---------------- coord (f32 exact) ----------------
  if (lane < 4) {
    int grow = r0 + w * 4 + lane;
    if (grow < N) {
      float cx[3], s[3];
#pragma unroll
      for (int d = 0; d < 3; ++d) { cx[d] = clipf(x[(size_t)grow * 3 + d]); s[d] = 0.f; }
      const float* tp = trans + (size_t)grow * 48;
#pragma unroll
      for (int q = 0; q < 12; ++q) {
        f32x4 v = *(const f32x4*)(tp + q * 4);
#pragma unroll
        for (int e = 0; e < 4; ++e) s[(q * 4 + e) % 3] += clipf(v[e]);
      }
#pragma unroll
      for (int d = 0; d < 3; ++d)
        coord_out[(size_t)grow * 3 + d] = cx[d] + s[d] * (1.f / 16.f);
    }
  }

  // ---------------- stage agg = [hh | sum_k edge] as bf16 ----------------
  // wave w handles row i0+w; 64 lanes cover 256 cols as float4.
#pragma unroll
  for (int i0 = 0; i0 < MT; i0 += 4) {
    int row = i0 + w;
    int grow = r0 + row;
    f32x4 ef = {0.f, 0.f, 0.f, 0.f};
    f32x4 hv = {0.f, 0.f, 0.f, 0.f};
    if (grow < N) {
      const float* ep = edge + (size_t)grow * (KNB * HNF) + lane * 4;
#pragma unroll
      for (int k = 0; k < KNB; ++k) ef += ldnt4(ep + k * HNF);   // nt: protect L2 wb
      hv = *(const f32x4*)(hh + (size_t)grow * HNF + lane * 4);
    }
    short4v hb, eb;
#pragma unroll
    for (int j = 0; j < 4; ++j) { hb[j] = f2bf(hv[j]); eb[j] = f2bf(ef[j]); }
    int sw = (row & 7) << 4;
    *(short4v*)(smem + ((row * 1024 + lane * 8) ^ sw)) = hb;
    *(short4v*)(smem + ((row * 1024 + 512 + lane * 8) ^ sw)) = eb;
  }
  __syncthreads();

  // ---------------- mat1: T = silu([hh|ef] @ W1 + b1) ----------------
  const int colbase = w * 64;
  const int mrow = lane & 15;    // A row / C col within 16-tile
  const int kslot = lane >> 4;   // k-slot within 32-step
  const short8* wf1 = (const short8*)wb;
  const short8* wf2 = (const short8*)(wb + W1E);

  f32x4 acc1[4];
#pragma unroll
  for (int nt = 0; nt < 4; ++nt) acc1[nt] = (f32x4){0.f, 0.f, 0.f, 0.f};

#pragma unroll 2
  for (int kk = 0; kk < 16; ++kk) {
    int k0 = kk * 32 + kslot * 8;
    int swa = (mrow & 7) << 4;
    short8 a = *(const short8*)(smem + ((mrow * 1024 + k0 * 2) ^ swa));
    const short8* base = wf1 + ((kk * 256 + colbase + mrow) * 4 + kslot);
#pragma unroll
    for (int nt = 0; nt < 4; ++nt)
      acc1[nt] = __builtin_amdgcn_mfma_f32_16x16x32_bf16(a, base[nt * 64], acc1[nt], 0, 0, 0);
  }

  float b1v[4];
#pragma unroll
  for (int nt = 0; nt < 4; ++nt) b1v[nt] = b1[colbase + nt * 16 + mrow];

  __syncthreads();   // all waves done reading ef fragments before T overwrites

  // silu + T write into the ef half (bytes row*1024+512.., swizzled).
  // C/D mapping: row=(lane>>4)*4+reg, col=lane&15 (+colbase+nt*16).
#pragma unroll
  for (int nt = 0; nt < 4; ++nt)
#pragma unroll
    for (int r = 0; r < 4; ++r) {
      float v = acc1[nt][r] + b1v[nt];
      v = v / (1.f + __expf(-v));
      int row = kslot * 4 + r;
      int col = colbase + nt * 16 + mrow;
      unsigned off = ((unsigned)(row * 1024 + 512 + col * 2)) ^ ((row & 7) << 4);
      *(short*)(smem + off) = f2bf(v);
    }
  __syncthreads();

  // ---------------- mat2: h = T @ W2 + b2 + hh(LDS) ----------------
  f32x4 acc2[4];
#pragma unroll
  for (int nt = 0; nt < 4; ++nt) acc2[nt] = (f32x4){0.f, 0.f, 0.f, 0.f};

#pragma unroll 2
  for (int kk = 0; kk < 8; ++kk) {
    int k0 = kk * 32 + kslot * 8;
    short8 a = *(const short8*)(smem + (((unsigned)(mrow * 1024 + 512 + k0 * 2)) ^ ((mrow & 7) << 4)));
    const short8* base = wf2 + ((kk * 256 + colbase + mrow) * 4 + kslot);
#pragma unroll
    for (int nt = 0; nt < 4; ++nt)
      acc2[nt] = __builtin_amdgcn_mfma_f32_16x16x32_bf16(a, base[nt * 64], acc2[nt], 0, 0, 0);
  }

#pragma unroll
  for (int nt = 0; nt < 4; ++nt) {
    int col = colbase + nt * 16 + mrow;
    float bv = b2[col];
#pragma unroll
    for (int r = 0; r < 4; ++r) {
      int row = kslot * 4 + r;
      int grow = r0 + row;
      if (grow < N) {
        // residual from the staged bf16 hh tile (hh half still intact)
        unsigned hoff = ((unsigned)(row * 1024 + col * 2)) ^ ((row & 7) << 4);
        float hres = bf2f(*(const short*)(smem + hoff));
        size_t idx = (size_t)grow * HNF + col;
        float res = acc2[nt][r] + bv + hres;
        __builtin_nontemporal_store(res, &h_out[idx]);
      }
    }
  }
}

// ---- fallback (ws too small for wb): inline weight conversion --------------
__device__ __forceinline__ short8 load_wfrag(const float* __restrict__ W, int k0, int col) {
  short8 r;
#pragma unroll
  for (int j = 0; j < 8; ++j) r[j] = f2bf(W[(size_t)(k0 + j) * 256 + col]);
  return r;
}

__global__ __launch_bounds__(256, 4) void agg_fallback(
    const float* __restrict__ x, const float* __restrict__ trans,
    const float* __restrict__ edge, const float* __restrict__ hh,
    const float* __restrict__ W1, const float* __restrict__ b1,
    const float* __restrict__ W2, const float* __restrict__ b2,
    float* __restrict__ coord_out, float* __restrict__ h_out, int N) {
  __shared__ __align__(16) char smem[32 * 512 * 2];
  const int t = threadIdx.x, w = t >> 6, lane = t & 63;
  const int r0 = blockIdx.x * 32;
  if (lane < 8) {
    int grow = r0 + w * 8 + lane;
    if (grow < N) {
      float cx[3], s[3];
#pragma unroll
      for (int d = 0; d < 3; ++d) { cx[d] = clipf(x[(size_t)grow * 3 + d]); s[d] = 0.f; }
      const float* tp = trans + (size_t)grow * 48;
#pragma unroll
      for (int q = 0; q < 12; ++q) {
        f32x4 v = *(const f32x4*)(tp + q * 4);
#pragma unroll
        for (int e = 0; e < 4; ++e) s[(q * 4 + e) % 3] += clipf(v[e]);
      }
#pragma unroll
      for (int d = 0; d < 3; ++d)
        coord_out[(size_t)grow * 3 + d] = cx[d] + s[d] * (1.f / 16.f);
    }
  }
#pragma unroll
  for (int i0 = 0; i0 < 32; i0 += 4) {
    int row = i0 + w, grow = r0 + row;
    f32x4 ef = {0.f, 0.f, 0.f, 0.f}, hv = {0.f, 0.f, 0.f, 0.f};
    if (grow < N) {
      const float* ep = edge + (size_t)grow * (16 * 256) + lane * 4;
#pragma unroll
      for (int k = 0; k < 16; ++k) ef += ldnt4(ep + k * 256);
      hv = *(const f32x4*)(hh + (size_t)grow * 256 + lane * 4);
    }
    short4v hb, ebv;
#pragma unroll
    for (int j = 0; j < 4; ++j) { hb[j] = f2bf(hv[j]); ebv[j] = f2bf(ef[j]); }
    int sw = (row & 7) << 4;
    *(short4v*)(smem + ((row * 1024 + lane * 8) ^ sw)) = hb;
    *(short4v*)(smem + ((row * 1024 + 512 + lane * 8) ^ sw)) = ebv;
  }
  __syncthreads();
  const int colbase = w * 64, mrow = lane & 15, kslot = lane >> 4, kgrp = kslot * 8;
  f32x4 acc1[2][4];
#pragma unroll
  for (int mt = 0; mt < 2; ++mt)
#pragma unroll
    for (int nt = 0; nt < 4; ++nt) acc1[mt][nt] = (f32x4){0.f, 0.f, 0.f, 0.f};
#pragma unroll 2
  for (int kk = 0; kk < 16; ++kk) {
    int k0 = kk * 32 + kgrp, swa = (mrow & 7) << 4;
    short8 a0 = *(const short8*)(smem + ((mrow * 1024 + k0 * 2) ^ swa));
    short8 a1 = *(const short8*)(smem + (((16 + mrow) * 1024 + k0 * 2) ^ swa));
#pragma unroll
    for (int nt = 0; nt < 4; ++nt) {
      short8 bw = load_wfrag(W1, k0, colbase + nt * 16 + mrow);
      acc1[0][nt] = __builtin_amdgcn_mfma_f32_16x16x32_bf16(a0, bw, acc1[0][nt], 0, 0, 0);
      acc1[1][nt] = __builtin_amdgcn_mfma_f32_16x16x32_bf16(a1, bw, acc1[1][nt], 0, 0, 0);
    }
  }
  float b1v[4];
#pragma unroll
  for (int nt = 0; nt < 4; ++nt) b1v[nt] = b1[colbase + nt * 16 + mrow];
  __syncthreads();
#pragma unroll
  for (int mt = 0; mt < 2; ++mt)
#pragma unroll
    for (int nt = 0; nt < 4; ++nt)
#pragma unroll
      for (int r = 0; r < 4; ++r) {
        float v = acc1[mt][nt][r] + b1v[nt];
        v = v / (1.f + __expf(-v));
        int row = mt * 16 + kslot * 4 + r, col = colbase + nt * 16 + mrow;
        *(short*)(smem + ((row * 512 + col * 2) ^ ((row & 7) << 4))) = f2bf(v);
      }
  __syncthreads();
  f32x4 acc2[2][4];
#pragma unroll
  for (int mt = 0; mt < 2; ++mt)
#pragma unroll
    for (int nt = 0; nt < 4; ++nt) acc2[mt][nt] = (f32x4){0.f, 0.f, 0.f, 0.f};
#pragma unroll 2
  for (int kk = 0; kk < 8; ++kk) {
    int k0 = kk * 32 + kgrp;
#pragma unroll
    for (int mt = 0; mt < 2; ++mt) {
      int arow = mt * 16 + mrow;
      short8 a = *(const short8*)(smem + ((arow * 512 + k0 * 2) ^ ((arow & 7) << 4)));
#pragma unroll
      for (int nt = 0; nt < 4; ++nt) {
        short8 bw = load_wfrag(W2, k0, colbase + nt * 16 + mrow);
        acc2[mt][nt] = __builtin_amdgcn_mfma_f32_16x16x32_bf16(a, bw, acc2[mt][nt], 0, 0, 0);
      }
    }
  }
#pragma unroll
  for (int mt = 0; mt < 2; ++mt)
#pragma unroll
    for (int nt = 0; nt < 4; ++nt) {
      int col = colbase + nt * 16 + mrow;
      float bv = b2[col];
#pragma unroll
      for (int r = 0; r < 4; ++r) {
        int row = mt * 16 + kslot * 4 + r, grow = r0 + row;
        if (grow < N) {
          size_t idx = (size_t)grow * 256 + col;
          h_out[idx] = acc2[mt][nt][r] + bv + hh[idx];
        }
      }
    }
}

extern "C" void kernel_launch(void* const* d_in, const int* in_sizes, int n_in,
                              void* d_out, int out_size, void* d_ws, size_t ws_size,
                              hipStream_t stream) {
  const float* x     = (const float*)d_in[0];
  const float* trans = (const float*)d_in[1];
  const float* edge  = (const float*)d_in[2];
  const float* hh    = (const float*)d_in[3];
  const float* W1    = (const float*)d_in[4];
  const float* b1    = (const float*)d_in[5];
  const float* W2    = (const float*)d_in[6];
  const float* b2    = (const float*)d_in[7];

  int N = in_sizes[0] / 3;
  float* coord_out = (float*)d_out;
  float* h_out = coord_out + (size_t)N * 3;

  if (ws_size >= WB_BYTES) {
    short* wb = (short*)d_ws;
    convw<<<(W1E + W2E) / 256, 256, 0, stream>>>(W1, W2, wb);
    agg_fused6<<<(N + MT - 1) / MT, 256, 0, stream>>>(x, trans, edge, hh, b1, b2, wb,
                                                      coord_out, h_out, N);
  } else {
    agg_fallback<<<(N + 31) / 32, 256, 0, stream>>>(x, trans, edge, hh, W1, b1, W2, b2,
                                                    coord_out, h_out, N);
  }
}

// Round 9
// 190.353 us; speedup vs baseline: 1.1120x; 1.0762x over previous
//
#include <hip/hip_runtime.h>

// Aggregationlayer: coord = clip(x) + mean_k clip(trans)
//                   h = hh + silu([hh | sum_k ef] @ W1 + b1) @ W2 + b2
// R8 = R5 (best, 195.4us) + mixed-tile tail smoothing:
//     1536 MT=32 tiles (=6 per CU exactly at 5 blocks/CU) + 53 MT=16 tail
//     tiles dispatched last -> makespan ~6.1T vs 7T (per-CU quantization).
//     Single kernel, block-uniform branch (two kernels would serialize).

typedef float f32x4 __attribute__((ext_vector_type(4)));
typedef short short8 __attribute__((ext_vector_type(8)));
typedef short short4v __attribute__((ext_vector_type(4)));

#define KNB 16
#define HNF 256
#define W1E (512 * 256)
#define W2E (256 * 256)
#define WB_BYTES ((size_t)(W1E + W2E) * 2)

__device__ __forceinline__ short f2bf(float f) {
  unsigned u = __builtin_bit_cast(unsigned, f);
  u += 0x7fffu + ((u >> 16) & 1u);   // round-to-nearest-even
  return (short)(u >> 16);
}

__device__ __forceinline__ float bf2f(short s) {
  unsigned u = ((unsigned)(unsigned short)s) << 16;
  return __builtin_bit_cast(float, u);
}

__device__ __forceinline__ float clipf(float v) {
  return fminf(fmaxf(v, -1000.f), 1000.f);
}

__device__ __forceinline__ f32x4 ldnt4(const float* p) {
  return __builtin_nontemporal_load((const f32x4*)p);
}

// ---- pre-kernel: f32 weights -> bf16 fragment layout -----------------------
// dst[(((k>>5)*256 + col)<<5) + ((k>>3)&3)*8 + (k&7)] = bf16(W[k][col])
__global__ void convw(const float* __restrict__ W1, const float* __restrict__ W2,
                      short* __restrict__ wb) {
  int i = blockIdx.x * 256 + threadIdx.x;
  const float* src; short* dst; int k, col;
  if (i < W1E) { src = W1; dst = wb; k = i >> 8; col = i & 255; }
  else         { int j = i - W1E; src = W2; dst = wb + W1E; k = j >> 8; col = j & 255; }
  short v = f2bf(src[((size_t)k << 8) | col]);
  dst[(((k >> 5) * 256 + col) << 5) + ((k >> 3) & 3) * 8 + (k & 7)] = v;
}

// ---- tile body, templated on rows-per-tile R (32 main / 16 tail) -----------
template <int R>
__device__ __forceinline__ void tile_body(
    const float* __restrict__ x, const float* __restrict__ trans,
    const float* __restrict__ edge, const float* __restrict__ hh,
    const float* __restrict__ b1, const float* __restrict__ b2,
    const short* __restrict__ wb,
    float* __restrict__ coord_out, float* __restrict__ h_out,
    int N, int r0, char* smem) {
  constexpr int MG = R / 16;   // MFMA row-groups (2 or 1)
  const int t = threadIdx.x;
  const int w = t >> 6, lane = t & 63;

  // ---------------- coord (f32 exact) ----------------
  if (lane < R / 4) {
    int grow = r0 + w * (R / 4) + lane;
    if (grow < N) {
      float cx[3], s[3];
#pragma unroll
      for (int d = 0; d < 3; ++d) { cx[d] = clipf(x[(size_t)grow * 3 + d]); s[d] = 0.f; }
      const float* tp = trans + (size_t)grow * 48;
#pragma unroll
      for (int q = 0; q < 12; ++q) {
        f32x4 v = *(const f32x4*)(tp + q * 4);
#pragma unroll
        for (int e = 0; e < 4; ++e) s[(q * 4 + e) % 3] += clipf(v[e]);
      }
#pragma unroll
      for (int d = 0; d < 3; ++d)
        coord_out[(size_t)grow * 3 + d] = cx[d] + s[d] * (1.f / 16.f);
    }
  }

  // ---------------- stage agg = [hh | sum_k edge] as bf16 ----------------
  // wave w handles row i0+w; 64 lanes cover 256 cols as float4.
#pragma unroll
  for (int i0 = 0; i0 < R; i0 += 4) {
    int row = i0 + w;
    int grow = r0 + row;
    f32x4 ef = {0.f, 0.f, 0.f, 0.f};
    f32x4 hv = {0.f, 0.f, 0.f, 0.f};
    if (grow < N) {
      const float* ep = edge + (size_t)grow * (KNB * HNF) + lane * 4;
#pragma unroll
      for (int k = 0; k < KNB; ++k) ef += ldnt4(ep + k * HNF);   // nt: protect L2 wb
      hv = *(const f32x4*)(hh + (size_t)grow * HNF + lane * 4);
    }
    short4v hb, eb;
#pragma unroll
    for (int j = 0; j < 4; ++j) { hb[j] = f2bf(hv[j]); eb[j] = f2bf(ef[j]); }
    int sw = (row & 7) << 4;
    *(short4v*)(smem + ((row * 1024 + lane * 8) ^ sw)) = hb;
    *(short4v*)(smem + ((row * 1024 + 512 + lane * 8) ^ sw)) = eb;
  }
  __syncthreads();

  // ---------------- mat1: T = silu([hh|ef] @ W1 + b1) ----------------
  const int colbase = w * 64;
  const int mrow = lane & 15;    // A row / C col within 16-tile
  const int kslot = lane >> 4;   // k-slot within 32-step
  const short8* wf1 = (const short8*)wb;
  const short8* wf2 = (const short8*)(wb + W1E);

  f32x4 acc1[MG][4];
#pragma unroll
  for (int mg = 0; mg < MG; ++mg)
#pragma unroll
    for (int nt = 0; nt < 4; ++nt) acc1[mg][nt] = (f32x4){0.f, 0.f, 0.f, 0.f};

#pragma unroll 2
  for (int kk = 0; kk < 16; ++kk) {
    int k0 = kk * 32 + kslot * 8;
    short8 a[MG];
#pragma unroll
    for (int mg = 0; mg < MG; ++mg) {
      int row = mg * 16 + mrow;
      a[mg] = *(const short8*)(smem + ((row * 1024 + k0 * 2) ^ ((row & 7) << 4)));
    }
    const short8* base = wf1 + ((kk * 256 + colbase + mrow) * 4 + kslot);
#pragma unroll
    for (int nt = 0; nt < 4; ++nt) {
      short8 bw = base[nt * 64];
#pragma unroll
      for (int mg = 0; mg < MG; ++mg)
        acc1[mg][nt] = __builtin_amdgcn_mfma_f32_16x16x32_bf16(a[mg], bw, acc1[mg][nt], 0, 0, 0);
    }
  }

  float b1v[4];
#pragma unroll
  for (int nt = 0; nt < 4; ++nt) b1v[nt] = b1[colbase + nt * 16 + mrow];

  __syncthreads();   // all waves done reading ef fragments before T overwrites

  // silu + T write into the ef half (bytes row*1024+512.., swizzled).
  // C/D mapping: row=(lane>>4)*4+reg (+mg*16), col=lane&15 (+colbase+nt*16).
#pragma unroll
  for (int mg = 0; mg < MG; ++mg)
#pragma unroll
    for (int nt = 0; nt < 4; ++nt)
#pragma unroll
      for (int r = 0; r < 4; ++r) {
        float v = acc1[mg][nt][r] + b1v[nt];
        v = v / (1.f + __expf(-v));
        int row = mg * 16 + kslot * 4 + r;
        int col = colbase + nt * 16 + mrow;
        unsigned off = ((unsigned)(row * 1024 + 512 + col * 2)) ^ ((row & 7) << 4);
        *(short*)(smem + off) = f2bf(v);
      }
  __syncthreads();

  // ---------------- mat2: h = T @ W2 + b2 + hh(LDS) ----------------
  f32x4 acc2[MG][4];
#pragma unroll
  for (int mg = 0; mg < MG; ++mg)
#pragma unroll
    for (int nt = 0; nt < 4; ++nt) acc2[mg][nt] = (f32x4){0.f, 0.f, 0.f, 0.f};

#pragma unroll 2
  for (int kk = 0; kk < 8; ++kk) {
    int k0 = kk * 32 + kslot * 8;
    const short8* base = wf2 + ((kk * 256 + colbase + mrow) * 4 + kslot);
#pragma unroll
    for (int mg = 0; mg < MG; ++mg) {
      int arow = mg * 16 + mrow;
      short8 a = *(const short8*)(smem + (((unsigned)(arow * 1024 + 512 + k0 * 2)) ^ ((arow & 7) << 4)));
#pragma unroll
      for (int nt = 0; nt < 4; ++nt)
        acc2[mg][nt] = __builtin_amdgcn_mfma_f32_16x16x32_bf16(a, base[nt * 64], acc2[mg][nt], 0, 0, 0);
    }
  }

#pragma unroll
  for (int nt = 0; nt < 4; ++nt) {
    int col = colbase + nt * 16 + mrow;
    float bv = b2[col];
#pragma unroll
    for (int mg = 0; mg < MG; ++mg)
#pragma unroll
      for (int r = 0; r < 4; ++r) {
        int row = mg * 16 + kslot * 4 + r;
        int grow = r0 + row;
        if (grow < N) {
          // residual from the staged bf16 hh tile (hh half still intact)
          unsigned hoff = ((unsigned)(row * 1024 + col * 2)) ^ ((row & 7) << 4);
          float hres = bf2f(*(const short*)(smem + hoff));
          size_t idx = (size_t)grow * HNF + col;
          float res = acc2[mg][nt][r] + bv + hres;
          __builtin_nontemporal_store(res, &h_out[idx]);
        }
      }
  }
}

// ---- fused main kernel: mixed tiles (32-row main, 16-row tail) -------------
__global__ __launch_bounds__(256, 5) void agg_mixed(
    const float* __restrict__ x, const float* __restrict__ trans,
    const float* __restrict__ edge, const float* __restrict__ hh,
    const float* __restrict__ b1, const float* __restrict__ b2,
    const short* __restrict__ wb,
    float* __restrict__ coord_out, float* __restrict__ h_out,
    int N, int nMain) {
  __shared__ __align__(16) char smem[32 * 1024];
  int b = blockIdx.x;
  if (b < nMain)
    tile_body<32>(x, trans, edge, hh, b1, b2, wb, coord_out, h_out, N, b * 32, smem);
  else
    tile_body<16>(x, trans, edge, hh, b1, b2, wb, coord_out, h_out, N,
                  nMain * 32 + (b - nMain) * 16, smem);
}

// ---- fallback (ws too small for wb): inline weight conversion --------------
__device__ __forceinline__ short8 load_wfrag(const float* __restrict__ W, int k0, int col) {
  short8 r;
#pragma unroll
  for (int j = 0; j < 8; ++j) r[j] = f2bf(W[(size_t)(k0 + j) * 256 + col]);
  return r;
}

__global__ __launch_bounds__(256, 4) void agg_fallback(
    const float* __restrict__ x, const float* __restrict__ trans,
    const float* __restrict__ edge, const float* __restrict__ hh,
    const float* __restrict__ W1, const float* __restrict__ b1,
    const float* __restrict__ W2, const float* __restrict__ b2,
    float* __restrict__ coord_out, float* __restrict__ h_out, int N) {
  __shared__ __align__(16) char smem[32 * 512 * 2];
  const int t = threadIdx.x, w = t >> 6, lane = t & 63;
  const int r0 = blockIdx.x * 32;
  if (lane < 8) {
    int grow = r0 + w * 8 + lane;
    if (grow < N) {
      float cx[3], s[3];
#pragma unroll
      for (int d = 0; d < 3; ++d) { cx[d] = clipf(x[(size_t)grow * 3 + d]); s[d] = 0.f; }
      const float* tp = trans + (size_t)grow * 48;
#pragma unroll
      for (int q = 0; q < 12; ++q) {
        f32x4 v = *(const f32x4*)(tp + q * 4);
#pragma unroll
        for (int e = 0; e < 4; ++e) s[(q * 4 + e) % 3] += clipf(v[e]);
      }
#pragma unroll
      for (int d = 0; d < 3; ++d)
        coord_out[(size_t)grow * 3 + d] = cx[d] + s[d] * (1.f / 16.f);
    }
  }
#pragma unroll
  for (int i0 = 0; i0 < 32; i0 += 4) {
    int row = i0 + w, grow = r0 + row;
    f32x4 ef = {0.f, 0.f, 0.f, 0.f}, hv = {0.f, 0.f, 0.f, 0.f};
    if (grow < N) {
      const float* ep = edge + (size_t)grow * (16 * 256) + lane * 4;
#pragma unroll
      for (int k = 0; k < 16; ++k) ef += ldnt4(ep + k * 256);
      hv = *(const f32x4*)(hh + (size_t)grow * 256 + lane * 4);
    }
    short4v hb, ebv;
#pragma unroll
    for (int j = 0; j < 4; ++j) { hb[j] = f2bf(hv[j]); ebv[j] = f2bf(ef[j]); }
    int sw = (row & 7) << 4;
    *(short4v*)(smem + ((row * 1024 + lane * 8) ^ sw)) = hb;
    *(short4v*)(smem + ((row * 1024 + 512 + lane * 8) ^ sw)) = ebv;
  }
  __syncthreads();
  const int colbase = w * 64, mrow = lane & 15, kslot = lane >> 4, kgrp = kslot * 8;
  f32x4 acc1[2][4];
#pragma unroll
  for (int mt = 0; mt < 2; ++mt)
#pragma unroll
    for (int nt = 0; nt < 4; ++nt) acc1[mt][nt] = (f32x4){0.f, 0.f, 0.f, 0.f};
#pragma unroll 2
  for (int kk = 0; kk < 16; ++kk) {
    int k0 = kk * 32 + kgrp, swa = (mrow & 7) << 4;
    short8 a0 = *(const short8*)(smem + ((mrow * 1024 + k0 * 2) ^ swa));
    short8 a1 = *(const short8*)(smem + (((16 + mrow) * 1024 + k0 * 2) ^ swa));
#pragma unroll
    for (int nt = 0; nt < 4; ++nt) {
      short8 bw = load_wfrag(W1, k0, colbase + nt * 16 + mrow);
      acc1[0][nt] = __builtin_amdgcn_mfma_f32_16x16x32_bf16(a0, bw, acc1[0][nt], 0, 0, 0);
      acc1[1][nt] = __builtin_amdgcn_mfma_f32_16x16x32_bf16(a1, bw, acc1[1][nt], 0, 0, 0);
    }
  }
  float b1v[4];
#pragma unroll
  for (int nt = 0; nt < 4; ++nt) b1v[nt] = b1[colbase + nt * 16 + mrow];
  __syncthreads();
#pragma unroll
  for (int mt = 0; mt < 2; ++mt)
#pragma unroll
    for (int nt = 0; nt < 4; ++nt)
#pragma unroll
      for (int r = 0; r < 4; ++r) {
        float v = acc1[mt][nt][r] + b1v[nt];
        v = v / (1.f + __expf(-v));
        int row = mt * 16 + kslot * 4 + r, col = colbase + nt * 16 + mrow;
        *(short*)(smem + ((row * 512 + col * 2) ^ ((row & 7) << 4))) = f2bf(v);
      }
  __syncthreads();
  f32x4 acc2[2][4];
#pragma unroll
  for (int mt = 0; mt < 2; ++mt)
#pragma unroll
    for (int nt = 0; nt < 4; ++nt) acc2[mt][nt] = (f32x4){0.f, 0.f, 0.f, 0.f};
#pragma unroll 2
  for (int kk = 0; kk < 8; ++kk) {
    int k0 = kk * 32 + kgrp;
#pragma unroll
    for (int mt = 0; mt < 2; ++mt) {
      int arow = mt * 16 + mrow;
      short8 a = *(const short8*)(smem + ((arow * 512 + k0 * 2) ^ ((arow & 7) << 4)));
#pragma unroll
      for (int nt = 0; nt < 4; ++nt) {
        short8 bw = load_wfrag(W2, k0, colbase + nt * 16 + mrow);
        acc2[mt][nt] = __builtin_amdgcn_mfma_f32_16x16x32_bf16(a, bw, acc2[mt][nt], 0, 0, 0);
      }
    }
  }
#pragma unroll
  for (int mt = 0; mt < 2; ++mt)
#pragma unroll
    for (int nt = 0; nt < 4; ++nt) {
      int col = colbase + nt * 16 + mrow;
      float bv = b2[col];
#pragma unroll
      for (int r = 0; r < 4; ++r) {
        int row = mt * 16 + kslot * 4 + r, grow = r0 + row;
        if (grow < N) {
          size_t idx = (size_t)grow * 256 + col;
          h_out[idx] = acc2[mt][nt][r] + bv + hh[idx];
        }
      }
    }
}

extern "C" void kernel_launch(void* const* d_in, const int* in_sizes, int n_in,
                              void* d_out, int out_size, void* d_ws, size_t ws_size,
                              hipStream_t stream) {
  const float* x     = (const float*)d_in[0];
  const float* trans = (const float*)d_in[1];
  const float* edge  = (const float*)d_in[2];
  const float* hh    = (const float*)d_in[3];
  const float* W1    = (const float*)d_in[4];
  const float* b1    = (const float*)d_in[5];
  const float* W2    = (const float*)d_in[6];
  const float* b2    = (const float*)d_in[7];

  int N = in_sizes[0] / 3;
  float* coord_out = (float*)d_out;
  float* h_out = coord_out + (size_t)N * 3;

  if (ws_size >= WB_BYTES) {
    short* wb = (short*)d_ws;
    convw<<<(W1E + W2E) / 256, 256, 0, stream>>>(W1, W2, wb);
    // main tiles: largest multiple of 256 tiles that fits entirely in N rows
    int nMain = ((N / 32) / 256) * 256;
    int remRows = N - nMain * 32;
    int nTail = (remRows + 15) / 16;
    agg_mixed<<<nMain + nTail, 256, 0, stream>>>(x, trans, edge, hh, b1, b2, wb,
                                                 coord_out, h_out, N, nMain);
  } else {
    agg_fallback<<<(N + 31) / 32, 256, 0, stream>>>(x, trans, edge, hh, W1, b1, W2, b2,
                                                    coord_out, h_out, N);
  }
}